// Round 11
// baseline (287.067 us; speedup 1.0000x reference)
//
#include <hip/hip_runtime.h>
#include <hip/hip_bf16.h>

#define NTOK   16384
#define INF    1024
#define OUTF   4096
#define NBLK   16
#define BLKSZ  256
#define KTOP   4

typedef short bf16x8 __attribute__((ext_vector_type(8)));
typedef float f32x4 __attribute__((ext_vector_type(4)));
typedef unsigned short u16x8 __attribute__((ext_vector_type(8)));

__device__ __forceinline__ unsigned short f2bf(float f) {
  unsigned u = __float_as_uint(f);
  u += 0x7FFFu + ((u >> 16) & 1u);
  return (unsigned short)(u >> 16);
}

__device__ __forceinline__ void load_lds16(const void* g, void* l) {
  __builtin_amdgcn_global_load_lds(
      (const __attribute__((address_space(1))) unsigned int*)g,
      (__attribute__((address_space(3))) unsigned int*)l, 16, 0, 0);
}

__device__ __forceinline__ double shfl_xor_d(double v, int m) {
  long long l = __double_as_longlong(v);
  int lo = (int)(l & 0xFFFFFFFFll), hi = (int)(l >> 32);
  lo = __shfl_xor(lo, m);
  hi = __shfl_xor(hi, m);
  return __longlong_as_double(((long long)hi << 32) | (unsigned long long)(unsigned)lo);
}

// pi(j): storage j = 128*wc + 8*c16 + ni  <->  original col = 128*wc + 16*ni + c16
__device__ __forceinline__ int pi_perm(int j) {
  return (j & 128) | ((j & 7) << 4) | ((j >> 3) & 15);
}

// ---------------- router + weight conversion fused ----------------
__global__ __launch_bounds__(256) void k_cvt_router(
    const float* __restrict__ x, const float* __restrict__ rw,
    const float* __restrict__ rb, const float* __restrict__ w1,
    const float* __restrict__ w2, const float* __restrict__ b1,
    unsigned* __restrict__ tok_blocks, unsigned* __restrict__ counts,
    unsigned short* __restrict__ xb, unsigned short* __restrict__ w1b,
    unsigned short* __restrict__ w2p, float* __restrict__ b1p) {
  __shared__ float4 rwl[4096];  // router_w [16][1024] fp32 = 64KB (reused as hist)
  const int tid = threadIdx.x;
  const float4* rw4 = (const float4*)rw;
  for (int i = tid; i < 4096; i += 256) rwl[i] = rw4[i];
  __syncthreads();

  const int n = blockIdx.x * 32 + (tid >> 3);
  const int q = tid & 7;
  double p[16];
#pragma unroll
  for (int j = 0; j < 16; ++j) p[j] = 0.0;
  const float4* xr = (const float4*)(x + (size_t)n * INF);
  ushort4* xbr = (ushort4*)(xb + (size_t)n * INF);
#pragma unroll 4
  for (int i = 0; i < 32; ++i) {
    const int d4 = q + i * 8;
    const float4 xv = xr[d4];
    ushort4 o;
    o.x = f2bf(xv.x); o.y = f2bf(xv.y); o.z = f2bf(xv.z); o.w = f2bf(xv.w);
    xbr[d4] = o;
#pragma unroll
    for (int j = 0; j < 16; ++j) {
      const float4 wv = rwl[j * 256 + d4];
      p[j] = fma((double)xv.x, (double)wv.x, p[j]);
      p[j] = fma((double)xv.y, (double)wv.y, p[j]);
      p[j] = fma((double)xv.z, (double)wv.z, p[j]);
      p[j] = fma((double)xv.w, (double)wv.w, p[j]);
    }
  }
#pragma unroll
  for (int j = 0; j < 16; ++j) {
    double v = p[j];
    v += shfl_xor_d(v, 1);
    v += shfl_xor_d(v, 2);
    v += shfl_xor_d(v, 4);
    p[j] = v + (double)rb[j];
  }

  __syncthreads();
  unsigned* hist = (unsigned*)rwl;
  if (tid < 16) hist[tid] = 0;
  __syncthreads();

  if (q == 0) {
    unsigned packed = 0;
#pragma unroll
    for (int j = 0; j < 16; ++j) {
      int r = 0;
#pragma unroll
      for (int j2 = 0; j2 < 16; ++j2)
        r += (int)((p[j2] > p[j]) | ((p[j2] == p[j]) & (j2 < j)));
      if (r < KTOP) packed |= (unsigned)j << (8 * r);
    }
    tok_blocks[n] = packed;
    atomicAdd(&hist[packed & 15u], 1u);
    atomicAdd(&hist[(packed >> 8) & 15u], 1u);
    atomicAdd(&hist[(packed >> 16) & 15u], 1u);
    atomicAdd(&hist[(packed >> 24) & 15u], 1u);
  }
  __syncthreads();
  if (tid < 16 && hist[tid]) atomicAdd(&counts[tid], hist[tid]);

  // ---- weight conversion (grid-stride tail) ----
  const size_t stride = (size_t)gridDim.x * 256;
  for (size_t i = (size_t)blockIdx.x * 256 + tid; i < 1573376; i += stride) {
    if (i < 1048576) {
      float4 v = ((const float4*)w1)[i];
      ushort4 o;
      o.x = f2bf(v.x); o.y = f2bf(v.y); o.z = f2bf(v.z); o.w = f2bf(v.w);
      ((ushort4*)w1b)[i] = o;
    } else if (i < 1572864) {
      const size_t g = i - 1048576;
      const int d = (int)(g >> 9);
      const int rest = (int)(g & 511);
      const int jg = rest * 8;
      const int blk = jg >> 8;
      const int j0 = jg & 255;
      const float* src = w2 + (size_t)d * 4096 + blk * 256;
      u16x8 o;
#pragma unroll
      for (int ni = 0; ni < 8; ++ni) o[ni] = f2bf(src[pi_perm(j0 + ni)]);
      *(u16x8*)(w2p + (size_t)d * 4096 + jg) = o;
    } else {
      const int idx = (int)(i - 1572864);
      const int jg = idx * 8;
      const int blk = jg >> 8;
      const int j0 = jg & 255;
      const float* src = b1 + blk * 256;
      float o[8];
#pragma unroll
      for (int ni = 0; ni < 8; ++ni) o[ni] = src[pi_perm(j0 + ni)];
      float4* dst = (float4*)(b1p + jg);
      dst[0] = make_float4(o[0], o[1], o[2], o[3]);
      dst[1] = make_float4(o[4], o[5], o[6], o[7]);
    }
  }
}

// ---------------- build per-block token lists (local prefix scan, slot bits) ----------------
__global__ __launch_bounds__(256) void k_build(
    const unsigned* __restrict__ tok_blocks, const unsigned* __restrict__ counts,
    unsigned* __restrict__ alloc, unsigned short* __restrict__ list) {
  unsigned offl[16];
  {
    unsigned o = 0;
#pragma unroll
    for (int i = 0; i < 16; ++i) { offl[i] = o; o += (counts[i] + 127u) & ~127u; }
  }
  const int n = blockIdx.x * 256 + threadIdx.x;
  const unsigned packed = tok_blocks[n];
  const int lane = threadIdx.x & 63;
#pragma unroll
  for (int b = 0; b < 16; ++b) {
    int r = -1;
#pragma unroll
    for (int q = 0; q < 4; ++q)
      if (((packed >> (8 * q)) & 15u) == (unsigned)b) r = q;
    unsigned long long m = __ballot(r >= 0);
    if (m) {
      int leader = __ffsll((unsigned long long)m) - 1;
      unsigned base = 0;
      if (lane == leader) base = offl[b] + atomicAdd(&alloc[b], (unsigned)__popcll(m));
      base = (unsigned)__shfl((int)base, leader);
      if (r >= 0) {
        unsigned pos = base + (unsigned)__popcll(m & ((1ull << lane) - 1ull));
        list[pos] = (unsigned short)(n | (r << 14));
      }
    }
  }
}

// ---------------- fused FFN: BM=64, BK=32, 256 thr, 72KB LDS -> 2 blocks/CU ----------------
// 4 waves as 2x2 grid, 32x128/wave (R8 fragment math). Cross-block overlap hides
// barrier drains (m114). Staging rows are 64B (4 chunks), XOR swizzle (row>>1)&3.
__global__ __launch_bounds__(256, 2) void k_ffn(
    const unsigned short* __restrict__ xb, const unsigned short* __restrict__ w1b,
    const unsigned short* __restrict__ w2p, const float* __restrict__ b1p,
    const unsigned short* __restrict__ list, const unsigned* __restrict__ counts,
    unsigned short* __restrict__ part) {
  // LDS (73728 B): h [0,32K) ; As0 @32K, As1 @36K (4KB each) ; Bs0 @40K, Bs1 @56K (16KB each)
  __shared__ __align__(16) char lds[73728];
  char* const As0 = lds + 32768;
  char* const As1 = lds + 36864;
  char* const Bs0 = lds + 40960;
  char* const Bs1 = lds + 57344;

  const int bid0 = blockIdx.x;
  const int bid = (bid0 & 7) * 256 + (bid0 >> 3);   // XCD swizzle: same-expert tiles share an XCD
  const int blk = bid >> 7;          // 128 tiles of 64 rows per expert
  const int tile = bid & 127;
  unsigned cnt = 0, goffBase = 0;
  {
    unsigned o = 0;
#pragma unroll
    for (int i = 0; i < 16; ++i) {
      const unsigned c = counts[i];
      if (i == blk) { cnt = c; goffBase = o; }
      o += (c + 127u) & ~127u;
    }
  }
  if ((unsigned)(tile * 64) >= cnt) return;
  const unsigned goff = goffBase + tile * 64;
  const int rem = (int)cnt - tile * 64;

  const int tid = threadIdx.x;
  const int lane = tid & 63;
  const int wid = tid >> 6;      // 0..3
  const int wr = wid >> 1;       // 0..1 : rows wr*32..+32
  const int wc = wid & 1;        // 0..1 : cols wc*128..+128
  const int c16 = lane & 15;
  const int kc = lane >> 4;      // 0..3 (K=32: 4 chunks of 8 bf16)

  // staging identity: 1 A-row chunk per thread
  const int srow = tid >> 2;            // 0..63
  const int schunk = tid & 3;
  const unsigned tokS = list[goff + srow] & 0x3FFFu;

#define STAGE_A(buf, k0)                                                        \
  load_lds16(xb + (size_t)tokS * INF + (k0) +                                   \
                 ((schunk ^ ((srow >> 1) & 3)) * 8),                            \
             (buf) + tid * 16);

#define STAGE_B1(buf, k0)                                                       \
  _Pragma("unroll")                                                             \
  for (int l = 0; l < 4; ++l) {                                                 \
    const int idx = l * 256 + tid;                                              \
    const int row = idx >> 2;                                                   \
    load_lds16(w1b + (size_t)(blk * 256 + row) * INF + (k0) +                   \
                   (((idx & 3) ^ ((row >> 1) & 3)) * 8),                        \
               (buf) + idx * 16);                                               \
  }

#define COMPUTE_A(abuf, bbuf)                                                   \
  {                                                                             \
    bf16x8 a[2], b[8];                                                          \
    _Pragma("unroll")                                                           \
    for (int mi = 0; mi < 2; ++mi) {                                            \
      const int row = wr * 32 + mi * 16 + c16;                                  \
      a[mi] = *(const bf16x8*)((abuf) + row * 64 +                              \
                               ((kc ^ ((row >> 1) & 3)) << 4));                 \
    }                                                                           \
    _Pragma("unroll")                                                           \
    for (int ni = 0; ni < 8; ++ni) {                                            \
      const int row = wc * 128 + ni * 16 + c16;                                 \
      b[ni] = *(const bf16x8*)((bbuf) + row * 64 +                              \
                               ((kc ^ ((row >> 1) & 3)) << 4));                 \
    }                                                                           \
    _Pragma("unroll")                                                           \
    for (int mi = 0; mi < 2; ++mi)                                              \
      _Pragma("unroll")                                                         \
      for (int ni = 0; ni < 8; ++ni)                                            \
        acc[mi][ni] =                                                           \
            __builtin_amdgcn_mfma_f32_16x16x32_bf16(a[mi], b[ni], acc[mi][ni], 0, 0, 0); \
  }

  // -------- phase A: fc1, 32 K-steps of 32 --------
  f32x4 acc[2][8] = {};
  STAGE_A(As0, 0);
  STAGE_B1(Bs0, 0);
  __syncthreads();
#pragma unroll 1
  for (int kk = 0; kk < 16; ++kk) {
    const int k0 = kk * 64;
    STAGE_A(As1, k0 + 32);
    STAGE_B1(Bs1, k0 + 32);
    COMPUTE_A(As0, Bs0);
    __syncthreads();
    if (kk < 15) {
      STAGE_A(As0, k0 + 64);
      STAGE_B1(Bs0, k0 + 64);
    }
    COMPUTE_A(As1, Bs1);
    __syncthreads();
  }

#define STAGE_B2(buf, it)                                                       \
  {                                                                             \
    const int ns2 = (it) >> 3, k02 = ((it) & 7) * 32;                           \
    _Pragma("unroll")                                                           \
    for (int l = 0; l < 4; ++l) {                                               \
      const int idx = l * 256 + tid;                                            \
      const int row = idx >> 2;                                                 \
      load_lds16(w2p + (size_t)(ns2 * 256 + row) * OUTF + blk * 256 + k02 +     \
                     (((idx & 3) ^ ((row >> 1) & 3)) * 8),                      \
                 (buf) + idx * 16);                                             \
    }                                                                           \
  }

#define COMPUTE_B(bbuf, k02)                                                    \
  {                                                                             \
    bf16x8 a[2], b[8];                                                          \
    _Pragma("unroll")                                                           \
    for (int mi = 0; mi < 2; ++mi) {                                            \
      const int row = wr * 32 + mi * 16 + c16;                                  \
      const int co = ((k02) >> 3) + kc;                                         \
      a[mi] = *(const bf16x8*)(lds + row * 512 +                                \
                               (((co & ~7) | ((co & 7) ^ (row & 7))) << 4));    \
    }                                                                           \
    _Pragma("unroll")                                                           \
    for (int ni = 0; ni < 8; ++ni) {                                            \
      const int row = wc * 128 + ni * 16 + c16;                                 \
      b[ni] = *(const bf16x8*)((bbuf) + row * 64 +                              \
                               ((kc ^ ((row >> 1) & 3)) << 4));                 \
    }                                                                           \
    _Pragma("unroll")                                                           \
    for (int mi = 0; mi < 2; ++mi)                                              \
      _Pragma("unroll")                                                         \
      for (int ni = 0; ni < 8; ++ni)                                            \
        acc2[mi][ni] =                                                          \
            __builtin_amdgcn_mfma_f32_16x16x32_bf16(a[mi], b[ni], acc2[mi][ni], 0, 0, 0); \
  }

  // stage phase-B's first tile while h is being written (Bs0 is dead now)
  STAGE_B2(Bs0, 0);

  // h = relu(acc + b1) -> LDS, pi-packed cols, XOR-swizzled 16B chunks (row stride 512B)
  {
    const float4* bp = (const float4*)(b1p + blk * 256 + wc * 128 + c16 * 8);
    const float4 bv0 = bp[0], bv1 = bp[1];
    const float bvv[8] = {bv0.x, bv0.y, bv0.z, bv0.w, bv1.x, bv1.y, bv1.z, bv1.w};
    const int chunk = wc * 16 + c16;  // 0..31
    const int cslot = (chunk & ~7);
    const int clow  = (chunk & 7);
#pragma unroll
    for (int mi = 0; mi < 2; ++mi) {
#pragma unroll
      for (int i = 0; i < 4; ++i) {
        const int row = wr * 32 + mi * 16 + (lane >> 4) * 4 + i;
        u16x8 wv;
#pragma unroll
        for (int ni = 0; ni < 8; ++ni) {
          float v = acc[mi][ni][i] + bvv[ni];
          v = v > 0.f ? v : 0.f;
          wv[ni] = f2bf(v);
        }
        *(u16x8*)(lds + row * 512 + ((cslot | (clow ^ (row & 7))) << 4)) = wv;
      }
    }
  }
  __syncthreads();  // h visible; Bs0's it=0 data drained

  // -------- phase B: fc2, 4 ns x 8 K-steps of 32 --------
#pragma unroll 1
  for (int ns = 0; ns < 4; ++ns) {
    f32x4 acc2[2][8] = {};
#pragma unroll 1
    for (int jj = 0; jj < 4; ++jj) {
      const int it = ns * 8 + jj * 2;
      STAGE_B2(Bs1, it + 1);
      COMPUTE_B(Bs0, jj * 64);
      __syncthreads();
      if (it + 2 < 32) STAGE_B2(Bs0, it + 2);
      COMPUTE_B(Bs1, jj * 64 + 32);
      __syncthreads();
    }
    // epilogue: scatter to part[(tok*4+slot)], 256B chunks, pad rows guarded
#pragma unroll
    for (int mi = 0; mi < 2; ++mi) {
#pragma unroll
      for (int i = 0; i < 4; ++i) {
        const int row = wr * 32 + mi * 16 + (lane >> 4) * 4 + i;
        if (row < rem) {
          const unsigned e = list[goff + row];
          u16x8 wv;
#pragma unroll
          for (int ni = 0; ni < 8; ++ni) wv[ni] = f2bf(acc2[mi][ni][i]);
          *(u16x8*)(part + ((size_t)(e & 0x3FFFu) * 4 + (e >> 14)) * 1024 +
                    ns * 256 + wc * 128 + c16 * 8) = wv;
        }
      }
    }
  }
#undef STAGE_A
#undef STAGE_B1
#undef STAGE_B2
#undef COMPUTE_A
#undef COMPUTE_B
}

// ---------------- reduce: out[tok][c] = b2[c] + sum_s part[(tok*4+s)][sigma(c)] ----------------
__global__ __launch_bounds__(256) void k_reduce(const unsigned short* __restrict__ part,
                                                const float* __restrict__ b2,
                                                float* __restrict__ out) {
  __shared__ float lds[8 * 1028];  // 8 tokens x 1024 (+4 pad)
  const int tid = threadIdx.x;
  const int tok0 = blockIdx.x * 8;
  const int tok_l = tid >> 5;
  const int l32 = tid & 31;
  const unsigned short* pbase = part + (size_t)(tok0 + tok_l) * 4096;

#pragma unroll
  for (int g = 0; g < 4; ++g) {
    const int idx = g * 32 + l32;          // p-group in [0,128)
    const int p0 = idx * 8;
    float s[8] = {0.f, 0.f, 0.f, 0.f, 0.f, 0.f, 0.f, 0.f};
#pragma unroll
    for (int sl = 0; sl < 4; ++sl) {
      u16x8 v = *(const u16x8*)(pbase + sl * 1024 + p0);
#pragma unroll
      for (int j = 0; j < 8; ++j)
        s[j] += __uint_as_float((unsigned)(unsigned short)v[j] << 16);
    }
    const int ns = idx >> 5, wcb = (idx >> 4) & 1, cc = idx & 15;
#pragma unroll
    for (int ni = 0; ni < 8; ++ni)
      lds[tok_l * 1028 + ns * 256 + wcb * 128 + ni * 16 + cc] = s[ni];
  }
  __syncthreads();
  const float4 b2v = ((const float4*)b2)[tid];
#pragma unroll
  for (int r = 0; r < 8; ++r) {
    f32x4 lv = *(f32x4*)&lds[r * 1028 + tid * 4];
    float4 o = make_float4(lv[0] + b2v.x, lv[1] + b2v.y, lv[2] + b2v.z, lv[3] + b2v.w);
    *(float4*)(out + (size_t)(tok0 + r) * 1024 + tid * 4) = o;
  }
}

extern "C" void kernel_launch(void* const* d_in, const int* in_sizes, int n_in,
                              void* d_out, int out_size, void* d_ws, size_t ws_size,
                              hipStream_t stream) {
  const float* x  = (const float*)d_in[0];
  const float* rw = (const float*)d_in[1];
  const float* rb = (const float*)d_in[2];
  const float* w1 = (const float*)d_in[3];
  const float* b1 = (const float*)d_in[4];
  const float* w2 = (const float*)d_in[5];
  const float* b2 = (const float*)d_in[6];
  float* out = (float*)d_out;

  char* ws = (char*)d_ws;
  unsigned short* part = (unsigned short*)(ws);              // 134,217,728 B
  unsigned short* xb   = (unsigned short*)(ws + 134217728);  //  33,554,432 B
  unsigned short* w1b  = (unsigned short*)(ws + 167772160);  //   8,388,608 B
  unsigned short* w2p  = (unsigned short*)(ws + 176160768);  //   8,388,608 B
  unsigned* tokb       = (unsigned*)(ws + 184549376);        //      65,536 B
  unsigned short* list = (unsigned short*)(ws + 184614912);  //     135,168 B
  float* b1p           = (float*)(ws + 184750080);           //      16,384 B
  unsigned* counts     = (unsigned*)(ws + 184766464);        //          64 B
  unsigned* alloc      = (unsigned*)(ws + 184766528);        //          64 B

  hipMemsetAsync(ws + 184766464, 0, 128, stream);
  k_cvt_router<<<dim3(512), dim3(256), 0, stream>>>(x, rw, rb, w1, w2, b1, tokb,
                                                    counts, xb, w1b, w2p, b1p);
  k_build<<<dim3(64), dim3(256), 0, stream>>>(tokb, counts, alloc, list);
  k_ffn<<<dim3(2048), dim3(256), 0, stream>>>(xb, w1b, w2p, b1p, list, counts, part);
  k_reduce<<<dim3(2048), dim3(256), 0, stream>>>(part, b2, out);
}

// Round 12
// 258.157 us; speedup vs baseline: 1.1120x; 1.1120x over previous
//
#include <hip/hip_runtime.h>
#include <hip/hip_bf16.h>

#define NTOK   16384
#define INF    1024
#define OUTF   4096
#define NBLK   16
#define BLKSZ  256
#define KTOP   4

typedef short bf16x8 __attribute__((ext_vector_type(8)));
typedef float f32x4 __attribute__((ext_vector_type(4)));
typedef unsigned short u16x8 __attribute__((ext_vector_type(8)));

__device__ __forceinline__ unsigned short f2bf(float f) {
  unsigned u = __float_as_uint(f);
  u += 0x7FFFu + ((u >> 16) & 1u);
  return (unsigned short)(u >> 16);
}

__device__ __forceinline__ void load_lds16(const void* g, void* l) {
  __builtin_amdgcn_global_load_lds(
      (const __attribute__((address_space(1))) unsigned int*)g,
      (__attribute__((address_space(3))) unsigned int*)l, 16, 0, 0);
}

__device__ __forceinline__ double shfl_xor_d(double v, int m) {
  long long l = __double_as_longlong(v);
  int lo = (int)(l & 0xFFFFFFFFll), hi = (int)(l >> 32);
  lo = __shfl_xor(lo, m);
  hi = __shfl_xor(hi, m);
  return __longlong_as_double(((long long)hi << 32) | (unsigned long long)(unsigned)lo);
}

// pi(j): storage j = 128*wc + 8*c16 + ni  <->  original col = 128*wc + 16*ni + c16
__device__ __forceinline__ int pi_perm(int j) {
  return (j & 128) | ((j & 7) << 4) | ((j >> 3) & 15);
}

// ---------------- router + weight conversion fused ----------------
__global__ __launch_bounds__(256) void k_cvt_router(
    const float* __restrict__ x, const float* __restrict__ rw,
    const float* __restrict__ rb, const float* __restrict__ w1,
    const float* __restrict__ w2, const float* __restrict__ b1,
    unsigned* __restrict__ tok_blocks, unsigned* __restrict__ counts,
    unsigned short* __restrict__ xb, unsigned short* __restrict__ w1b,
    unsigned short* __restrict__ w2p, float* __restrict__ b1p) {
  __shared__ float4 rwl[4096];  // router_w [16][1024] fp32 = 64KB (reused as hist)
  const int tid = threadIdx.x;
  const float4* rw4 = (const float4*)rw;
  for (int i = tid; i < 4096; i += 256) rwl[i] = rw4[i];
  __syncthreads();

  const int n = blockIdx.x * 32 + (tid >> 3);
  const int q = tid & 7;
  double p[16];
#pragma unroll
  for (int j = 0; j < 16; ++j) p[j] = 0.0;
  const float4* xr = (const float4*)(x + (size_t)n * INF);
  ushort4* xbr = (ushort4*)(xb + (size_t)n * INF);
#pragma unroll 4
  for (int i = 0; i < 32; ++i) {
    const int d4 = q + i * 8;
    const float4 xv = xr[d4];
    ushort4 o;
    o.x = f2bf(xv.x); o.y = f2bf(xv.y); o.z = f2bf(xv.z); o.w = f2bf(xv.w);
    xbr[d4] = o;
#pragma unroll
    for (int j = 0; j < 16; ++j) {
      const float4 wv = rwl[j * 256 + d4];
      p[j] = fma((double)xv.x, (double)wv.x, p[j]);
      p[j] = fma((double)xv.y, (double)wv.y, p[j]);
      p[j] = fma((double)xv.z, (double)wv.z, p[j]);
      p[j] = fma((double)xv.w, (double)wv.w, p[j]);
    }
  }
#pragma unroll
  for (int j = 0; j < 16; ++j) {
    double v = p[j];
    v += shfl_xor_d(v, 1);
    v += shfl_xor_d(v, 2);
    v += shfl_xor_d(v, 4);
    p[j] = v + (double)rb[j];
  }

  __syncthreads();
  unsigned* hist = (unsigned*)rwl;
  if (tid < 16) hist[tid] = 0;
  __syncthreads();

  if (q == 0) {
    unsigned packed = 0;
#pragma unroll
    for (int j = 0; j < 16; ++j) {
      int r = 0;
#pragma unroll
      for (int j2 = 0; j2 < 16; ++j2)
        r += (int)((p[j2] > p[j]) | ((p[j2] == p[j]) & (j2 < j)));
      if (r < KTOP) packed |= (unsigned)j << (8 * r);
    }
    tok_blocks[n] = packed;
    atomicAdd(&hist[packed & 15u], 1u);
    atomicAdd(&hist[(packed >> 8) & 15u], 1u);
    atomicAdd(&hist[(packed >> 16) & 15u], 1u);
    atomicAdd(&hist[(packed >> 24) & 15u], 1u);
  }
  __syncthreads();
  if (tid < 16 && hist[tid]) atomicAdd(&counts[tid], hist[tid]);

  // ---- weight conversion (grid-stride tail) ----
  const size_t stride = (size_t)gridDim.x * 256;
  for (size_t i = (size_t)blockIdx.x * 256 + tid; i < 1573376; i += stride) {
    if (i < 1048576) {
      float4 v = ((const float4*)w1)[i];
      ushort4 o;
      o.x = f2bf(v.x); o.y = f2bf(v.y); o.z = f2bf(v.z); o.w = f2bf(v.w);
      ((ushort4*)w1b)[i] = o;
    } else if (i < 1572864) {
      const size_t g = i - 1048576;
      const int d = (int)(g >> 9);
      const int rest = (int)(g & 511);
      const int jg = rest * 8;
      const int blk = jg >> 8;
      const int j0 = jg & 255;
      const float* src = w2 + (size_t)d * 4096 + blk * 256;
      u16x8 o;
#pragma unroll
      for (int ni = 0; ni < 8; ++ni) o[ni] = f2bf(src[pi_perm(j0 + ni)]);
      *(u16x8*)(w2p + (size_t)d * 4096 + jg) = o;
    } else {
      const int idx = (int)(i - 1572864);
      const int jg = idx * 8;
      const int blk = jg >> 8;
      const int j0 = jg & 255;
      const float* src = b1 + blk * 256;
      float o[8];
#pragma unroll
      for (int ni = 0; ni < 8; ++ni) o[ni] = src[pi_perm(j0 + ni)];
      float4* dst = (float4*)(b1p + jg);
      dst[0] = make_float4(o[0], o[1], o[2], o[3]);
      dst[1] = make_float4(o[4], o[5], o[6], o[7]);
    }
  }
}

// ---------------- build per-block token lists (local prefix scan, slot bits) ----------------
__global__ __launch_bounds__(256) void k_build(
    const unsigned* __restrict__ tok_blocks, const unsigned* __restrict__ counts,
    unsigned* __restrict__ alloc, unsigned short* __restrict__ list) {
  unsigned offl[16];
  {
    unsigned o = 0;
#pragma unroll
    for (int i = 0; i < 16; ++i) { offl[i] = o; o += (counts[i] + 127u) & ~127u; }
  }
  const int n = blockIdx.x * 256 + threadIdx.x;
  const unsigned packed = tok_blocks[n];
  const int lane = threadIdx.x & 63;
#pragma unroll
  for (int b = 0; b < 16; ++b) {
    int r = -1;
#pragma unroll
    for (int q = 0; q < 4; ++q)
      if (((packed >> (8 * q)) & 15u) == (unsigned)b) r = q;
    unsigned long long m = __ballot(r >= 0);
    if (m) {
      int leader = __ffsll((unsigned long long)m) - 1;
      unsigned base = 0;
      if (lane == leader) base = offl[b] + atomicAdd(&alloc[b], (unsigned)__popcll(m));
      base = (unsigned)__shfl((int)base, leader);
      if (r >= 0) {
        unsigned pos = base + (unsigned)__popcll(m & ((1ull << lane) - 1ull));
        list[pos] = (unsigned short)(n | (r << 14));
      }
    }
  }
}

// ---------------- fused FFN (R8 schedule): dbuf prefetch, h in LDS ----------------
// Phase A: h = relu(Xg @ W1blk^T + b1) -> LDS (pi-permuted, XOR-swizzled)
// Phase B: part[(tok*4+slot)] = h @ W2blk^T, A-fragments hoisted to registers
__global__ __launch_bounds__(512, 1) void k_ffn(
    const unsigned short* __restrict__ xb, const unsigned short* __restrict__ w1b,
    const unsigned short* __restrict__ w2p, const float* __restrict__ b1p,
    const unsigned short* __restrict__ list, const unsigned* __restrict__ counts,
    unsigned short* __restrict__ part) {
  // LDS: [0,64K) h ; As0 @64K, As1 @80K (16K each) ; Bs0 @96K, Bs1 @128K (32K each)
  __shared__ __align__(16) char lds[163840];
  char* const As0 = lds + 65536;
  char* const As1 = lds + 81920;
  char* const Bs0 = lds + 98304;
  char* const Bs1 = lds + 131072;

  const int bid0 = blockIdx.x;
  const int bid = (bid0 & 7) * 256 + (bid0 >> 3);   // XCD swizzle
  const int blk = bid >> 7;
  const int tile = bid & 127;
  unsigned cnt = 0, goffBase = 0;
  {
    unsigned o = 0;
#pragma unroll
    for (int i = 0; i < 16; ++i) {
      const unsigned c = counts[i];
      if (i == blk) { cnt = c; goffBase = o; }
      o += (c + 127u) & ~127u;
    }
  }
  if ((unsigned)(tile * 128) >= cnt) return;
  const unsigned goff = goffBase + tile * 128;
  const int rem = (int)cnt - tile * 128;

  const int tid = threadIdx.x;
  const int lane = tid & 63;
  const int wid = tid >> 6;      // 0..7
  const int wr = wid >> 1;       // 0..3 : rows wr*32..+32
  const int wc = wid & 1;        // 0..1 : cols wc*128..+128
  const int asl = tid & 7;
  const int c16 = lane & 15;

  // token rows this thread stages
  const unsigned tok0 = list[goff + (tid >> 3)] & 0x3FFFu;
  const unsigned tok1 = list[goff + 64 + (tid >> 3)] & 0x3FFFu;
  const int arow0 = tid >> 3;
  const int arow1 = 64 + arow0;

  // epilogue scatter entries (token|slot) for the 8 output rows this thread owns
  unsigned ep[2][4];
#pragma unroll
  for (int mi = 0; mi < 2; ++mi)
#pragma unroll
    for (int i = 0; i < 4; ++i)
      ep[mi][i] = list[goff + wr * 32 + mi * 16 + (lane >> 4) * 4 + i];

#define STAGE_A(buf, k0)                                                        \
  {                                                                             \
    load_lds16(xb + (size_t)tok0 * INF + (k0) + (asl ^ (arow0 & 7)) * 8,        \
               (buf) + (wid * 64) * 16);                                        \
    load_lds16(xb + (size_t)tok1 * INF + (k0) + (asl ^ (arow1 & 7)) * 8,        \
               (buf) + (512 + wid * 64) * 16);                                  \
  }

#define STAGE_B1(buf, k0)                                                       \
  _Pragma("unroll")                                                             \
  for (int r = 0; r < 4; ++r) {                                                 \
    const int row = (r * 512 + tid) >> 3;                                       \
    load_lds16(w1b + ((size_t)(blk * 256 + row)) * INF + (k0) +                 \
                   (asl ^ (row & 7)) * 8,                                       \
               (buf) + (r * 512 + wid * 64) * 16);                              \
  }

#define COMPUTE_A(abuf, bbuf)                                                   \
  _Pragma("unroll")                                                             \
  for (int ks = 0; ks < 2; ++ks) {                                              \
    const int kc = ks * 4 + (lane >> 4);                                        \
    bf16x8 a[2], b[8];                                                          \
    _Pragma("unroll")                                                           \
    for (int mi = 0; mi < 2; ++mi) {                                            \
      const int row = wr * 32 + mi * 16 + c16;                                  \
      a[mi] = *(const bf16x8*)((abuf) + row * 128 + ((kc ^ (row & 7)) << 4));   \
    }                                                                           \
    _Pragma("unroll")                                                           \
    for (int ni = 0; ni < 8; ++ni) {                                            \
      const int row = wc * 128 + ni * 16 + c16;                                 \
      b[ni] = *(const bf16x8*)((bbuf) + row * 128 + ((kc ^ (row & 7)) << 4));   \
    }                                                                           \
    _Pragma("unroll")                                                           \
    for (int mi = 0; mi < 2; ++mi)                                              \
      _Pragma("unroll")                                                         \
      for (int ni = 0; ni < 8; ++ni)                                            \
        acc[mi][ni] =                                                           \
            __builtin_amdgcn_mfma_f32_16x16x32_bf16(a[mi], b[ni], acc[mi][ni], 0, 0, 0); \
  }

  // -------- phase A: fc1 --------
  f32x4 acc[2][8] = {};
  STAGE_A(As0, 0);
  STAGE_B1(Bs0, 0);
  __syncthreads();
#pragma unroll 1
  for (int kk = 0; kk < 8; ++kk) {
    const int k0 = kk * 128;
    STAGE_A(As1, k0 + 64);
    STAGE_B1(Bs1, k0 + 64);
    COMPUTE_A(As0, Bs0);
    __syncthreads();
    if (kk < 7) {
      STAGE_A(As0, k0 + 128);
      STAGE_B1(Bs0, k0 + 128);
    }
    COMPUTE_A(As1, Bs1);
    __syncthreads();
  }

#define STAGE_B2(buf, it)                                                       \
  {                                                                             \
    const int ns2 = (it) >> 2, k02 = ((it) & 3) * 64;                           \
    _Pragma("unroll")                                                           \
    for (int r = 0; r < 4; ++r) {                                               \
      const int row = (r * 512 + tid) >> 3;                                     \
      load_lds16(w2p + (size_t)(ns2 * 256 + row) * OUTF + blk * 256 + k02 +     \
                     (asl ^ (row & 7)) * 8,                                     \
                 (buf) + (r * 512 + wid * 64) * 16);                            \
    }                                                                           \
  }

// phase-B MFMA using hoisted A-fragments pa[mi][ks][kg]
#define COMPUTE_B(bbuf, kg)                                                     \
  _Pragma("unroll")                                                             \
  for (int ks = 0; ks < 2; ++ks) {                                              \
    const int kc = ks * 4 + (lane >> 4);                                        \
    bf16x8 b[8];                                                                \
    _Pragma("unroll")                                                           \
    for (int ni = 0; ni < 8; ++ni) {                                            \
      const int row = wc * 128 + ni * 16 + c16;                                 \
      b[ni] = *(const bf16x8*)((bbuf) + row * 128 + ((kc ^ (row & 7)) << 4));   \
    }                                                                           \
    _Pragma("unroll")                                                           \
    for (int mi = 0; mi < 2; ++mi)                                              \
      _Pragma("unroll")                                                         \
      for (int ni = 0; ni < 8; ++ni)                                            \
        acc2[mi][ni] = __builtin_amdgcn_mfma_f32_16x16x32_bf16(                 \
            pa[mi][ks][kg], b[ni], acc2[mi][ni], 0, 0, 0);                      \
  }

  // stage phase-B's first tile while h is being written (Bs0 is dead now)
  STAGE_B2(Bs0, 0);

  // h = relu(acc + b1) -> LDS, pi-permuted cols, XOR-swizzled 16B chunks (row stride 512B)
  {
    const float4* bp = (const float4*)(b1p + blk * 256 + wc * 128 + c16 * 8);
    const float4 bv0 = bp[0], bv1 = bp[1];
    const float bvv[8] = {bv0.x, bv0.y, bv0.z, bv0.w, bv1.x, bv1.y, bv1.z, bv1.w};
    const int chunk = wc * 16 + c16;  // 0..31
    const int cslot = (chunk & ~7);
    const int clow  = (chunk & 7);
#pragma unroll
    for (int mi = 0; mi < 2; ++mi) {
#pragma unroll
      for (int i = 0; i < 4; ++i) {
        const int row = wr * 32 + mi * 16 + (lane >> 4) * 4 + i;
        u16x8 wv;
#pragma unroll
        for (int ni = 0; ni < 8; ++ni) {
          float v = acc[mi][ni][i] + bvv[ni];
          v = v > 0.f ? v : 0.f;
          wv[ni] = f2bf(v);
        }
        *(u16x8*)(lds + row * 512 + ((cslot | (clow ^ (row & 7))) << 4)) = wv;
      }
    }
  }
  __syncthreads();  // h visible; Bs0's it=0 data drained

  // hoist this wave's 16 h A-fragments into registers (constant across all ns)
  bf16x8 pa[2][2][4];
#pragma unroll
  for (int mi = 0; mi < 2; ++mi) {
    const int row = wr * 32 + mi * 16 + c16;
#pragma unroll
    for (int ks = 0; ks < 2; ++ks) {
      const int kc = ks * 4 + (lane >> 4);
#pragma unroll
      for (int kg = 0; kg < 4; ++kg)
        pa[mi][ks][kg] = *(const bf16x8*)(lds + row * 512 + kg * 128 +
                                          ((kc ^ (row & 7)) << 4));
    }
  }

  // -------- phase B: fc2 --------
#pragma unroll 1
  for (int ns = 0; ns < 4; ++ns) {
    f32x4 acc2[2][8] = {};
    const int it0 = ns * 4;
    STAGE_B2(Bs1, it0 + 1);
    COMPUTE_B(Bs0, 0);
    __syncthreads();
    STAGE_B2(Bs0, it0 + 2);
    COMPUTE_B(Bs1, 1);
    __syncthreads();
    STAGE_B2(Bs1, it0 + 3);
    COMPUTE_B(Bs0, 2);
    __syncthreads();
    if (ns < 3) STAGE_B2(Bs0, it0 + 4);
    COMPUTE_B(Bs1, 3);
    __syncthreads();
    // epilogue: scatter to part[(tok*4+slot)], 256B chunks, pad rows guarded
#pragma unroll
    for (int mi = 0; mi < 2; ++mi) {
#pragma unroll
      for (int i = 0; i < 4; ++i) {
        const int row = wr * 32 + mi * 16 + (lane >> 4) * 4 + i;
        if (row < rem) {
          const unsigned e = ep[mi][i];
          u16x8 wv;
#pragma unroll
          for (int ni = 0; ni < 8; ++ni) wv[ni] = f2bf(acc2[mi][ni][i]);
          *(u16x8*)(part + ((size_t)(e & 0x3FFFu) * 4 + (e >> 14)) * 1024 +
                    ns * 256 + wc * 128 + c16 * 8) = wv;
        }
      }
    }
  }
#undef STAGE_A
#undef STAGE_B1
#undef STAGE_B2
#undef COMPUTE_A
#undef COMPUTE_B
}

// ---------------- reduce: out[tok][c] = b2[c] + sum_s part[(tok*4+s)][sigma(c)] ----------------
__global__ __launch_bounds__(256) void k_reduce(const unsigned short* __restrict__ part,
                                                const float* __restrict__ b2,
                                                float* __restrict__ out) {
  __shared__ float lds[8 * 1028];  // 8 tokens x 1024 (+4 pad)
  const int tid = threadIdx.x;
  const int tok0 = blockIdx.x * 8;
  const int tok_l = tid >> 5;
  const int l32 = tid & 31;
  const unsigned short* pbase = part + (size_t)(tok0 + tok_l) * 4096;

#pragma unroll
  for (int g = 0; g < 4; ++g) {
    const int idx = g * 32 + l32;          // p-group in [0,128)
    const int p0 = idx * 8;
    float s[8] = {0.f, 0.f, 0.f, 0.f, 0.f, 0.f, 0.f, 0.f};
#pragma unroll
    for (int sl = 0; sl < 4; ++sl) {
      u16x8 v = *(const u16x8*)(pbase + sl * 1024 + p0);
#pragma unroll
      for (int j = 0; j < 8; ++j)
        s[j] += __uint_as_float((unsigned)(unsigned short)v[j] << 16);
    }
    const int ns = idx >> 5, wcb = (idx >> 4) & 1, cc = idx & 15;
#pragma unroll
    for (int ni = 0; ni < 8; ++ni)
      lds[tok_l * 1028 + ns * 256 + wcb * 128 + ni * 16 + cc] = s[ni];
  }
  __syncthreads();
  const float4 b2v = ((const float4*)b2)[tid];
#pragma unroll
  for (int r = 0; r < 8; ++r) {
    f32x4 lv = *(f32x4*)&lds[r * 1028 + tid * 4];
    float4 o = make_float4(lv[0] + b2v.x, lv[1] + b2v.y, lv[2] + b2v.z, lv[3] + b2v.w);
    *(float4*)(out + (size_t)(tok0 + r) * 1024 + tid * 4) = o;
  }
}

extern "C" void kernel_launch(void* const* d_in, const int* in_sizes, int n_in,
                              void* d_out, int out_size, void* d_ws, size_t ws_size,
                              hipStream_t stream) {
  const float* x  = (const float*)d_in[0];
  const float* rw = (const float*)d_in[1];
  const float* rb = (const float*)d_in[2];
  const float* w1 = (const float*)d_in[3];
  const float* b1 = (const float*)d_in[4];
  const float* w2 = (const float*)d_in[5];
  const float* b2 = (const float*)d_in[6];
  float* out = (float*)d_out;

  char* ws = (char*)d_ws;
  unsigned short* part = (unsigned short*)(ws);              // 134,217,728 B
  unsigned short* xb   = (unsigned short*)(ws + 134217728);  //  33,554,432 B
  unsigned short* w1b  = (unsigned short*)(ws + 167772160);  //   8,388,608 B
  unsigned short* w2p  = (unsigned short*)(ws + 176160768);  //   8,388,608 B
  unsigned* tokb       = (unsigned*)(ws + 184549376);        //      65,536 B
  unsigned short* list = (unsigned short*)(ws + 184614912);  //     135,168 B
  float* b1p           = (float*)(ws + 184750080);           //      16,384 B
  unsigned* counts     = (unsigned*)(ws + 184766464);        //          64 B
  unsigned* alloc      = (unsigned*)(ws + 184766528);        //          64 B

  hipMemsetAsync(ws + 184766464, 0, 128, stream);
  k_cvt_router<<<dim3(512), dim3(256), 0, stream>>>(x, rw, rb, w1, w2, b1, tokb,
                                                    counts, xb, w1b, w2p, b1p);
  k_build<<<dim3(64), dim3(256), 0, stream>>>(tokb, counts, alloc, list);
  k_ffn<<<dim3(2048), dim3(512), 0, stream>>>(xb, w1b, w2p, b1p, list, counts, part);
  k_reduce<<<dim3(2048), dim3(256), 0, stream>>>(part, b2, out);
}